// Round 10
// baseline (1012.690 us; speedup 1.0000x reference)
//
#include <hip/hip_runtime.h>
#include <hip/hip_bf16.h>

#define THREADS 1024

typedef __hip_bfloat16 bf16;
typedef __attribute__((ext_vector_type(4))) float f32x4;
typedef __attribute__((ext_vector_type(8))) short bf16x8;

#define MFMA __builtin_amdgcn_mfma_f32_16x16x32_bf16

// ---- LDS layout (bf16 elems), blocks of 512 = one fragment tile (16 batch x 32 K)
// All buffers: read slot[p], write slot[q], p = t&1.
#define O_A1  0       // 2 slots x 4mt : K=[x(2)|h1(16)|k18=1|pad]
#define O_AY  4096    // 2 slots x 4mt x 2kc : K=[y(36)|k36=1|pad]
#define O_AT1 12288   // 2 slots x 4mt x 2kc : t1(64)
#define O_A2  20480   // 4mt x 10 chunks [kc*2+slot], K=[l2(72)|h2(72)|k144=1|pad]
#define O_AH3 40960   // 2 slots x 4mt : h3(32)
#define LDS_ELEMS 45056
#define LDS_BYTES (LDS_ELEMS * 2)   // 90112

// self-consistent K mapping within a fragment tile (verified rounds 1-9)
__device__ __forceinline__ int kmap(int l, int j) {
    return (((l >> 4) & 3) << 2) + (j & 3) + ((j >> 2) << 4);
}
__device__ __forceinline__ int frag_off(int m, int k) { // k in [0,32)
    int l = (m & 15) | (((k >> 2) & 3) << 4);
    int j = (k & 3) | (((k >> 4) & 1) << 2);
    return (l << 3) + j;
}
__device__ __forceinline__ void st_frag(bf16* sbase, int KC, int m, int k, float v) {
    sbase[(((m >> 4) * KC + (k >> 5)) << 9) + frag_off(m, k & 31)] = __float2bfloat16(v);
}
__device__ __forceinline__ void st_frag_c(bf16* sbase, int KC, int m, int cidx, int kl, float v) {
    sbase[(((m >> 4) * KC + cidx) << 9) + frag_off(m, kl)] = __float2bfloat16(v);
}

__device__ __forceinline__ float rcp_(float x) { return __builtin_amdgcn_rcpf(x); }

// swapped-operand gate EW: lane's acc = {i,f,g,o} preacts (bias MFMA-folded). 4 exp + 3 rcp.
__device__ __forceinline__ float lstm_ew1(f32x4 acc, float& cst) {
    float ei = __expf(-acc[0]);
    float ef = __expf(-acc[1]);
    float eg = __expf(2.0f * fminf(acc[2], 40.0f));
    float eo = __expf(-acc[3]);
    float c = rcp_(1.0f + ef) * cst + (eg - 1.0f) * rcp_((1.0f + ei) * (eg + 1.0f));
    cst = c;
    float ec = __expf(2.0f * fminf(c, 40.0f));
    return (ec - 1.0f) * rcp_((1.0f + eo) * (ec + 1.0f));
}

__device__ __forceinline__ ushort bfu(float f) {
    union { bf16 b; ushort u; } v; v.b = __float2bfloat16(f); return v.u;
}

template <typename F>
__device__ __forceinline__ bf16x8 mk_frag(int lane, F val) { // val(k), k in [0,32)
    union { bf16x8 v; bf16 h[8]; } u;
#pragma unroll
    for (int j = 0; j < 8; ++j) u.h[j] = __float2bfloat16(val(kmap(lane, j)));
    return u.v;
}

__global__ void __launch_bounds__(THREADS, 4)
lstm_fused(const float* __restrict__ x, const float* __restrict__ y,
           const float* __restrict__ Wih1, const float* __restrict__ Whh1,
           const float* __restrict__ bih1, const float* __restrict__ bhh1,
           const float* __restrict__ Wih2, const float* __restrict__ Whh2,
           const float* __restrict__ bih2, const float* __restrict__ bhh2,
           const float* __restrict__ Wih3, const float* __restrict__ Whh3,
           const float* __restrict__ bih3, const float* __restrict__ bhh3,
           const float* __restrict__ W1, const float* __restrict__ b1,
           const float* __restrict__ W2, const float* __restrict__ b2,
           const float* __restrict__ W3, const float* __restrict__ b3,
           const float* __restrict__ W4, const float* __restrict__ b4,
           float* __restrict__ out) {
    extern __shared__ char smem[];
    bf16* sb = (bf16*)smem;
    const int tid = threadIdx.x;
    const int wave = tid >> 6, lane = tid & 63, ln15 = lane & 15;
    const int b0 = blockIdx.x * 64;

    // ---- wave roles (16 waves; one shared weight array W[13] = union 52 regs) ----
    // w0-3 : L2 x2 (nt 2w, 2w+1)                 W[0..4], W[5..9]
    // w4-7 : L2 (nt w+4) W[0..4] + L1 (nt w-4) W[5] ; w4: FC2-tail nt4 W[6..7]; w5: x-stage
    // w8-13: L2 (nt w+4) W[0..4] + L3 (nt w-8) W[5..9]; w8-11: FC34 (mt w-8) W[10]
    // w14-15: L3 (nt w-8) W[0..4] + FC1 x2 W[5..8] + FC2 x2 W[9..12] + y-stage
    bf16x8 W[13];
#pragma unroll
    for (int i = 0; i < 13; ++i) W[i] = bf16x8{0, 0, 0, 0, 0, 0, 0, 0};

    { // LSTM2 fills: K=[l2 72|h2 72|bias@144|pad]
        auto l2frag = [&](int nt, int kc) {
            int R = (nt << 4) + ln15;
            int r = (R & 3) * 72 + (R >> 2);
            float bias = bih2[r] + bhh2[r];
            return mk_frag(lane, [&](int kl) {
                int k = kc * 32 + kl;
                return k < 72 ? Wih2[r * 72 + k]
                     : (k < 144 ? Whh2[r * 72 + (k - 72)]
                     : (k == 144 ? bias : 0.0f)); });
        };
        if (wave < 4) {
#pragma unroll
            for (int kc = 0; kc < 5; ++kc) W[kc] = l2frag(2 * wave, kc);
#pragma unroll
            for (int kc = 0; kc < 5; ++kc) W[5 + kc] = l2frag(2 * wave + 1, kc);
        } else if (wave < 14) {
#pragma unroll
            for (int kc = 0; kc < 5; ++kc) W[kc] = l2frag(wave + 4, kc);
        }
    }
    if (wave >= 4 && wave < 8) { // LSTM1: K=[x 2|h1 16|bias@18|pad]
        int R = ((wave - 4) << 4) + ln15;
        int r = (R & 3) * 16 + (R >> 2);
        float bias = bih1[r] + bhh1[r];
        W[5] = mk_frag(lane, [&](int k) {
            return k < 2 ? Wih1[r * 2 + k]
                 : (k < 18 ? Whh1[r * 16 + (k - 2)]
                 : (k == 18 ? bias : 0.0f)); });
    }
    if (wave == 4) { // FC2 tail nt=4
        int n = 64 + ln15;
#pragma unroll
        for (int kc = 0; kc < 2; ++kc)
            W[6 + kc] = mk_frag(lane, [&](int kl) {
                return (n < 72) ? W2[n * 64 + kc * 32 + kl] : 0.0f; });
    }
    { // LSTM3 fills
        auto l3fill = [&](int base) {
            int R = ((wave - 8) << 4) + ln15;
            int r = (R & 3) * 32 + (R >> 2);
            float bias = bih3[r] + bhh3[r];
            W[base + 0] = mk_frag(lane, [&](int k) {
                return (k >= 2 && k < 18) ? Wih3[r * 88 + (k - 2)] : (k == 18 ? bias : 0.0f); });
            W[base + 1] = mk_frag(lane, [&](int k) {
                return (k >= 8) ? Wih3[r * 88 + 8 + k] : 0.0f; });
            W[base + 2] = mk_frag(lane, [&](int k) { return Wih3[r * 88 + 40 + k]; });
            W[base + 3] = mk_frag(lane, [&](int k) {
                return (k < 16) ? Wih3[r * 88 + 72 + k] : 0.0f; });
            W[base + 4] = mk_frag(lane, [&](int k) { return Whh3[r * 32 + k]; });
        };
        if (wave >= 8 && wave < 14) l3fill(5);
        else if (wave >= 14) l3fill(0);
    }
    if (wave >= 8 && wave < 12) // FC3
        W[10] = mk_frag(lane, [&](int k) { return W3[ln15 * 32 + k]; });
    if (wave >= 14) { // FC1 (nt 2(w-14), 2(w-14)+1) + FC2 (same nts)
#pragma unroll
        for (int nn = 0; nn < 2; ++nn) {
            int n = ((2 * (wave - 14) + nn) << 4) + ln15;
            float bias = b1[n];
#pragma unroll
            for (int kc = 0; kc < 2; ++kc)
                W[5 + 2 * nn + kc] = mk_frag(lane, [&](int kl) {
                    int k = kc * 32 + kl;
                    return k < 36 ? W1[n * 36 + k] : (k == 36 ? bias : 0.0f); });
#pragma unroll
            for (int kc = 0; kc < 2; ++kc)
                W[9 + 2 * nn + kc] = mk_frag(lane, [&](int kl) {
                    return W2[n * 64 + kc * 32 + kl]; });
        }
    }

    // ---- zero LDS ----
    {
        int4* z = (int4*)sb;
        int4 zv = {0, 0, 0, 0};
        for (int i = tid; i < LDS_BYTES / 16; i += THREADS) z[i] = zv;
    }
    __syncthreads();
    // ---- prologue stage: y(0)->AY[0], y(1)->AY[1], x(0)->A1[0], bias lanes ----
    for (int it = tid; it < 2 * 2304; it += THREADS) {
        int slot = it / 2304, r2 = it - slot * 2304;
        int m = r2 / 36, k = r2 - m * 36;
        st_frag(sb + O_AY + ((slot * 8) << 9), 2, m, k,
                y[(size_t)(b0 + m) * 900 + slot * 36 + k]);
    }
    if (tid < 128) {
        int m = tid >> 1, k = tid & 1;
        st_frag(sb + O_A1, 1, m, k, x[(size_t)(b0 + m) * 50 + k]);
    }
    {
        const bf16 one = __float2bfloat16(1.0f);
        if (tid < 128) { // A1 k=18, both slots
            int s = tid >> 6, mt = (tid >> 4) & 3, n = tid & 15;
            sb[O_A1 + ((s * 4 + mt) << 9) + frag_off(n, 18)] = one;
        } else if (tid < 256) { // AY k=36 (kc1, kl=4), both slots
            int i = tid - 128; int s = i >> 6, mt = (i >> 4) & 3, n = i & 15;
            sb[O_AY + ((s * 8 + mt * 2 + 1) << 9) + frag_off(n, 4)] = one;
        } else if (tid < 384) { // A2 k=144 (chunk 8+slot, kl=16), both slots
            int i = tid - 256; int s = i >> 6, mt = (i >> 4) & 3, n = i & 15;
            sb[O_A2 + ((mt * 10 + 8 + s) << 9) + frag_off(n, 16)] = one;
        }
    }
    __syncthreads();
    // ---- prologue FC1(0)->AT1[1], FC1(1)->AT1[0] on w14-15 ----
    if (wave >= 14) {
#pragma unroll
        for (int nn = 0; nn < 2; ++nn) {
            const int nf0 = ((2 * (wave - 14) + nn) << 4) + ((lane >> 4) << 2);
#pragma unroll
            for (int s = 0; s < 2; ++s) {
#pragma unroll
                for (int mt = 0; mt < 4; ++mt) {
                    f32x4 acc = {0.f, 0.f, 0.f, 0.f};
                    bf16x8 a0 = *(const bf16x8*)(sb + O_AY + ((s * 8 + mt * 2 + 0) << 9) + (lane << 3));
                    bf16x8 a1 = *(const bf16x8*)(sb + O_AY + ((s * 8 + mt * 2 + 1) << 9) + (lane << 3));
                    acc = MFMA(W[5 + 2 * nn], a0, acc, 0, 0, 0);
                    acc = MFMA(W[6 + 2 * nn], a1, acc, 0, 0, 0);
                    int batch = (mt << 4) + ln15;
#pragma unroll
                    for (int r = 0; r < 4; ++r)
                        st_frag(sb + O_AT1 + (((s ^ 1) * 8) << 9), 2, batch, nf0 + r, fmaxf(acc[r], 0.0f));
                }
            }
        }
    }
    __syncthreads();
    // ---- prologue FC2(0)->A2 l2 slot0 (w14,w15,w4); y(2)->AY[0] (w14-15) ----
    if (wave >= 14) {
#pragma unroll
        for (int nn = 0; nn < 2; ++nn) {
            const int nb = ((2 * (wave - 14) + nn) << 4) + ((lane >> 4) << 2);
            float4 bv = *(const float4*)(b2 + nb);
#pragma unroll
            for (int mt = 0; mt < 4; ++mt) {
                f32x4 acc = {0.f, 0.f, 0.f, 0.f};
                bf16x8 a0 = *(const bf16x8*)(sb + O_AT1 + ((8 + mt * 2 + 0) << 9) + (lane << 3));
                bf16x8 a1 = *(const bf16x8*)(sb + O_AT1 + ((8 + mt * 2 + 1) << 9) + (lane << 3));
                acc = MFMA(W[9 + 2 * nn], a0, acc, 0, 0, 0);
                acc = MFMA(W[10 + 2 * nn], a1, acc, 0, 0, 0);
                int batch = (mt << 4) + ln15;
#pragma unroll
                for (int r = 0; r < 4; ++r) {
                    int n = nb + r;
                    st_frag_c(sb + O_A2, 10, batch, ((n >> 5) << 1), n & 31, acc[r] + bv[r]);
                }
            }
        }
        const int m = ((wave - 14) << 5) + (lane >> 1);
        const int mt = m >> 4;
        const float* yp = y + (size_t)(b0 + m) * 900 + 2 * 36;
#pragma unroll
        for (int c = (lane & 1); c < 9; c += 2) {
            float4 v = *(const float4*)(yp + 4 * c);
            ushort4 pk;
            pk.x = bfu(v.x); pk.y = bfu(v.y); pk.z = bfu(v.z); pk.w = bfu(v.w);
            int k0 = 4 * c, kc = k0 >> 5;
            int l2v = (m & 15) | (((k0 >> 2) & 3) << 4);
            int j0 = ((k0 >> 4) & 1) << 2;
            *(ushort4*)((ushort*)(sb + O_AY) + ((mt * 2 + kc) << 9) + (l2v << 3) + j0) = pk;
        }
    } else if (wave == 4) {
        const int nb = 64 + ((lane >> 4) << 2);
        float4 bv = {0.f, 0.f, 0.f, 0.f};
        if (nb < 72) bv = *(const float4*)(b2 + nb);
#pragma unroll
        for (int mt = 0; mt < 4; ++mt) {
            f32x4 acc = {0.f, 0.f, 0.f, 0.f};
            bf16x8 a0 = *(const bf16x8*)(sb + O_AT1 + ((8 + mt * 2 + 0) << 9) + (lane << 3));
            bf16x8 a1 = *(const bf16x8*)(sb + O_AT1 + ((8 + mt * 2 + 1) << 9) + (lane << 3));
            acc = MFMA(W[6], a0, acc, 0, 0, 0);
            acc = MFMA(W[7], a1, acc, 0, 0, 0);
            if (nb < 72) {
                int batch = (mt << 4) + ln15;
#pragma unroll
                for (int r = 0; r < 4; ++r) {
                    int n = nb + r;
                    st_frag_c(sb + O_A2, 10, batch, ((n >> 5) << 1), n & 31, acc[r] + bv[r]);
                }
            }
        }
    }
    float cA[4] = {};   // L2-primary state (w0-13) / L3 state (w14-15)
    float cB[4] = {};   // w0-3: L2-secondary; w4-7: L1; w8-13: L3
    __syncthreads();

// LSTM3 body macro (weights + state chosen per role, constant indices)
#define L3_BODY(W0, W1, W2_, W3_, W4_, CST)                                              \
    {                                                                                     \
        const int nt3 = wave - 8;                                                         \
        _Pragma("unroll")                                                                 \
        for (int mt = 0; mt < 4; ++mt) {                                                  \
            f32x4 acc = {0.f, 0.f, 0.f, 0.f};                                             \
            bf16x8 a0 = *(const bf16x8*)(sb + O_A1 + ((p * 4 + mt) << 9) + (lane << 3));  \
            acc = MFMA(W0, a0, acc, 0, 0, 0);                                             \
            bf16x8 a1 = *(const bf16x8*)(sb + O_A2 + ((mt * 10 + 4 + p) << 9) + (lane << 3)); \
            acc = MFMA(W1, a1, acc, 0, 0, 0);                                             \
            bf16x8 a2 = *(const bf16x8*)(sb + O_A2 + ((mt * 10 + 6 + p) << 9) + (lane << 3)); \
            acc = MFMA(W2_, a2, acc, 0, 0, 0);                                            \
            bf16x8 a3 = *(const bf16x8*)(sb + O_A2 + ((mt * 10 + 8 + p) << 9) + (lane << 3)); \
            acc = MFMA(W3_, a3, acc, 0, 0, 0);                                            \
            bf16x8 a4 = *(const bf16x8*)(sb + O_AH3 + ((p * 4 + mt) << 9) + (lane << 3)); \
            acc = MFMA(W4_, a4, acc, 0, 0, 0);                                            \
            float hv = lstm_ew1(acc, CST[mt]);                                            \
            int batch = (mt << 4) + ln15;                                                 \
            st_frag(sb + O_AH3 + ((q * 4) << 9), 1, batch, (nt3 << 2) + (lane >> 4), hv); \
        }                                                                                 \
    }

    // ======== main loop: ONE barrier per phase ========
    for (int t = 0; t <= 25; ++t) {
        const int p = t & 1, q = p ^ 1;

        // ---- LSTM2(t) on w0-13, t<=24 ----
        if (t <= 24 && wave < 14) {
            const int ntA = (wave < 4) ? 2 * wave : wave + 4;
#pragma unroll
            for (int mt = 0; mt < 4; ++mt) {
                bf16x8 al[5];
#pragma unroll
                for (int b = 0; b < 5; ++b)
                    al[b] = *(const bf16x8*)(sb + O_A2 + ((mt * 10 + 2 * b + p) << 9) + (lane << 3));
                {
                    f32x4 acc = {0.f, 0.f, 0.f, 0.f};
#pragma unroll
                    for (int b = 0; b < 5; ++b) acc = MFMA(W[b], al[b], acc, 0, 0, 0);
                    float hv = lstm_ew1(acc, cA[mt]);
                    int batch = (mt << 4) + ln15;
                    int k = 72 + (ntA << 2) + (lane >> 4);
                    st_frag_c(sb + O_A2, 10, batch, ((k >> 5) << 1) + q, k & 31, hv);
                }
                if (wave < 4) {
                    f32x4 acc = {0.f, 0.f, 0.f, 0.f};
#pragma unroll
                    for (int b = 0; b < 5; ++b) acc = MFMA(W[5 + b], al[b], acc, 0, 0, 0);
                    float hv = lstm_ew1(acc, cB[mt]);
                    int batch = (mt << 4) + ln15;
                    int k = 72 + ((2 * wave + 1) << 2) + (lane >> 4);
                    st_frag_c(sb + O_A2, 10, batch, ((k >> 5) << 1) + q, k & 31, hv);
                }
            }
        }

        // ---- LSTM1(t) on w4-7, t<=24 ----
        if (t <= 24 && wave >= 4 && wave < 8) {
            const int nt1 = wave - 4;
#pragma unroll
            for (int mt = 0; mt < 4; ++mt) {
                bf16x8 a = *(const bf16x8*)(sb + O_A1 + ((p * 4 + mt) << 9) + (lane << 3));
                f32x4 acc = {0.f, 0.f, 0.f, 0.f};
                acc = MFMA(W[5], a, acc, 0, 0, 0);
                float hv = lstm_ew1(acc, cB[mt]);
                int batch = (mt << 4) + ln15;
                st_frag(sb + O_A1 + ((q * 4) << 9), 1, batch, 2 + (nt1 << 2) + (lane >> 4), hv);
            }
        }
        // ---- x(t+1) stage on w5, t<=23 ----
        if (wave == 5 && t <= 23) {
            const int m = lane, mt = m >> 4;
            float2 xv = *(const float2*)(x + (size_t)(b0 + m) * 50 + (t + 1) * 2);
            union { uint u; ushort s[2]; } xu;
            xu.s[0] = bfu(xv.x); xu.s[1] = bfu(xv.y);
            *(uint*)((ushort*)(sb + O_A1) + ((q * 4 + mt) << 9) + ((m & 15) << 3)) = xu.u;
        }
        // ---- FC1(t+2) on w14-15, t<=22 ----
        if (t <= 22 && wave >= 14) {
#pragma unroll
            for (int nn = 0; nn < 2; ++nn) {
                const int nf0 = ((2 * (wave - 14) + nn) << 4) + ((lane >> 4) << 2);
#pragma unroll
                for (int mt = 0; mt < 4; ++mt) {
                    f32x4 acc = {0.f, 0.f, 0.f, 0.f};
                    bf16x8 a0 = *(const bf16x8*)(sb + O_AY + ((p * 8 + mt * 2 + 0) << 9) + (lane << 3));
                    bf16x8 a1 = *(const bf16x8*)(sb + O_AY + ((p * 8 + mt * 2 + 1) << 9) + (lane << 3));
                    acc = MFMA(W[5 + 2 * nn], a0, acc, 0, 0, 0);
                    acc = MFMA(W[6 + 2 * nn], a1, acc, 0, 0, 0);
                    int batch = (mt << 4) + ln15;
#pragma unroll
                    for (int r = 0; r < 4; ++r)
                        st_frag(sb + O_AT1 + ((q * 8) << 9), 2, batch, nf0 + r, fmaxf(acc[r], 0.0f));
                }
            }
        }
        // ---- y(t+3) stage on w14-15, t<=21 ----
        if (wave >= 14 && t <= 21) {
            const int m = ((wave - 14) << 5) + (lane >> 1);
            const int mt = m >> 4;
            const float* yp = y + (size_t)(b0 + m) * 900 + (t + 3) * 36;
#pragma unroll
            for (int c = (lane & 1); c < 9; c += 2) {
                float4 v = *(const float4*)(yp + 4 * c);
                ushort4 pk;
                pk.x = bfu(v.x); pk.y = bfu(v.y); pk.z = bfu(v.z); pk.w = bfu(v.w);
                int k0 = 4 * c, kc = k0 >> 5;
                int l2v = (m & 15) | (((k0 >> 2) & 3) << 4);
                int j0 = ((k0 >> 4) & 1) << 2;
                *(ushort4*)((ushort*)(sb + O_AY) + ((q * 8 + mt * 2 + kc) << 9) + (l2v << 3) + j0) = pk;
            }
        }
        // ---- LSTM3(t-1) on w8-15, 1<=t<=25 ----
        if (t >= 1 && wave >= 8) {
            if (wave < 14) L3_BODY(W[5], W[6], W[7], W[8], W[9], cB)
            else           L3_BODY(W[0], W[1], W[2], W[3], W[4], cA)
        }
        // ---- FC2(t+1) on w14-15 & w4, t<=23 ----
        if (t <= 23) {
            if (wave >= 14) {
#pragma unroll
                for (int nn = 0; nn < 2; ++nn) {
                    const int nb = ((2 * (wave - 14) + nn) << 4) + ((lane >> 4) << 2);
                    float4 bv = *(const float4*)(b2 + nb);
#pragma unroll
                    for (int mt = 0; mt < 4; ++mt) {
                        f32x4 acc = {0.f, 0.f, 0.f, 0.f};
                        bf16x8 a0 = *(const bf16x8*)(sb + O_AT1 + ((p * 8 + mt * 2 + 0) << 9) + (lane << 3));
                        bf16x8 a1 = *(const bf16x8*)(sb + O_AT1 + ((p * 8 + mt * 2 + 1) << 9) + (lane << 3));
                        acc = MFMA(W[9 + 2 * nn], a0, acc, 0, 0, 0);
                        acc = MFMA(W[10 + 2 * nn], a1, acc, 0, 0, 0);
                        int batch = (mt << 4) + ln15;
#pragma unroll
                        for (int r = 0; r < 4; ++r) {
                            int n = nb + r;
                            st_frag_c(sb + O_A2, 10, batch, ((n >> 5) << 1) + q, n & 31, acc[r] + bv[r]);
                        }
                    }
                }
            } else if (wave == 4) {
                const int nb = 64 + ((lane >> 4) << 2);
                float4 bv = {0.f, 0.f, 0.f, 0.f};
                if (nb < 72) bv = *(const float4*)(b2 + nb);
#pragma unroll
                for (int mt = 0; mt < 4; ++mt) {
                    f32x4 acc = {0.f, 0.f, 0.f, 0.f};
                    bf16x8 a0 = *(const bf16x8*)(sb + O_AT1 + ((p * 8 + mt * 2 + 0) << 9) + (lane << 3));
                    bf16x8 a1 = *(const bf16x8*)(sb + O_AT1 + ((p * 8 + mt * 2 + 1) << 9) + (lane << 3));
                    acc = MFMA(W[6], a0, acc, 0, 0, 0);
                    acc = MFMA(W[7], a1, acc, 0, 0, 0);
                    if (nb < 72) {
                        int batch = (mt << 4) + ln15;
#pragma unroll
                        for (int r = 0; r < 4; ++r) {
                            int n = nb + r;
                            st_frag_c(sb + O_A2, 10, batch, ((n >> 5) << 1) + q, n & 31, acc[r] + bv[r]);
                        }
                    }
                }
            }
        }
        // ---- FC3+FC4(t-2) on w8-11, t>=2 ----
        if (t >= 2 && wave >= 8 && wave < 12) {
            const int mt = wave - 8, qd = lane >> 4;
            float4 b3v = *(const float4*)(b3 + 4 * qd);
            float4 w0v = *(const float4*)(W4 + 4 * qd);
            float4 w1v = *(const float4*)(W4 + 16 + 4 * qd);
            bf16x8 bb = *(const bf16x8*)(sb + O_AH3 + ((p * 4 + mt) << 9) + (lane << 3));
            f32x4 acc = {0.f, 0.f, 0.f, 0.f};
            acc = MFMA(W[10], bb, acc, 0, 0, 0);
            float s0 = 0.f, s1 = 0.f;
#pragma unroll
            for (int r = 0; r < 4; ++r) {
                float u = fmaxf(acc[r] + b3v[r], 0.0f);
                s0 = fmaf(u, w0v[r], s0);
                s1 = fmaf(u, w1v[r], s1);
            }
            s0 += __shfl_xor(s0, 16); s0 += __shfl_xor(s0, 32);
            s1 += __shfl_xor(s1, 16); s1 += __shfl_xor(s1, 32);
            if (lane < 16) {
                float2 o; o.x = s0 + b4[0]; o.y = s1 + b4[1];
                *(float2*)(out + (size_t)(b0 + (mt << 4) + lane) * 50 + (t - 2) * 2) = o;
            }
        }
        __syncthreads();
    }

    // ---- epilogue: FC3+FC4 for t=24; h3(24) written phase 25 -> slot 0 ----
    if (wave >= 8 && wave < 12) {
        const int mt = wave - 8, qd = lane >> 4;
        float4 b3v = *(const float4*)(b3 + 4 * qd);
        float4 w0v = *(const float4*)(W4 + 4 * qd);
        float4 w1v = *(const float4*)(W4 + 16 + 4 * qd);
        bf16x8 bb = *(const bf16x8*)(sb + O_AH3 + (mt << 9) + (lane << 3));
        f32x4 acc = {0.f, 0.f, 0.f, 0.f};
        acc = MFMA(W[10], bb, acc, 0, 0, 0);
        float s0 = 0.f, s1 = 0.f;
#pragma unroll
        for (int r = 0; r < 4; ++r) {
            float u = fmaxf(acc[r] + b3v[r], 0.0f);
            s0 = fmaf(u, w0v[r], s0);
            s1 = fmaf(u, w1v[r], s1);
        }
        s0 += __shfl_xor(s0, 16); s0 += __shfl_xor(s0, 32);
        s1 += __shfl_xor(s1, 16); s1 += __shfl_xor(s1, 32);
        if (lane < 16) {
            float2 o; o.x = s0 + b4[0]; o.y = s1 + b4[1];
            *(float2*)(out + (size_t)(b0 + (mt << 4) + lane) * 50 + 24 * 2) = o;
        }
    }
}

extern "C" void kernel_launch(void* const* d_in, const int* in_sizes, int n_in,
                              void* d_out, int out_size, void* d_ws, size_t ws_size,
                              hipStream_t stream) {
    (void)in_sizes; (void)n_in; (void)d_ws; (void)ws_size; (void)out_size;
    hipFuncSetAttribute((const void*)lstm_fused,
                        hipFuncAttributeMaxDynamicSharedMemorySize, LDS_BYTES);
    lstm_fused<<<dim3(2048), dim3(THREADS), LDS_BYTES, stream>>>(
        (const float*)d_in[0], (const float*)d_in[1],
        (const float*)d_in[2], (const float*)d_in[3],
        (const float*)d_in[4], (const float*)d_in[5],
        (const float*)d_in[6], (const float*)d_in[7],
        (const float*)d_in[8], (const float*)d_in[9],
        (const float*)d_in[10], (const float*)d_in[11],
        (const float*)d_in[12], (const float*)d_in[13],
        (const float*)d_in[14], (const float*)d_in[15],
        (const float*)d_in[16], (const float*)d_in[17],
        (const float*)d_in[18], (const float*)d_in[19],
        (const float*)d_in[20], (const float*)d_in[21],
        (float*)d_out);
}

// Round 11
// 944.304 us; speedup vs baseline: 1.0724x; 1.0724x over previous
//
#include <hip/hip_runtime.h>
#include <hip/hip_bf16.h>

#define THREADS 1024

typedef __hip_bfloat16 bf16;
typedef __attribute__((ext_vector_type(4))) float f32x4;
typedef __attribute__((ext_vector_type(16))) float f32x16;
typedef __attribute__((ext_vector_type(8))) short bf16x8;

#define MFMA32 __builtin_amdgcn_mfma_f32_32x32x16_bf16
#define Z16 f32x16{0.f,0.f,0.f,0.f,0.f,0.f,0.f,0.f,0.f,0.f,0.f,0.f,0.f,0.f,0.f,0.f}

// ---- LDS: blocks of 512 bf16 = one 32-col x 16-k B-fragment tile.
// Buffers double-slotted: read slot p=t&1, write slot q=p^1.
#define O_A1  0       // 2nt x 2kc x 2s : K=[x(2)|h1(16)|bias@18|pad]
#define O_AY  4096    // 2nt x 3kc x 2s : K=[y(36)|bias@36|pad]
#define O_AT1 10240   // 2nt x 5kc x 2s : K=[t1(64)|bias@64|pad]
#define O_A2  20480   // 2nt x 10kc x 2s: K=[l2(72)|h2(72)|bias@144|pad]
#define O_AH3 40960   // 2nt x 2kc x 2s : K=h3(32)
#define LDS_ELEMS 45056
#define LDS_BYTES (LDS_ELEMS * 2)   // 90112

__device__ __forceinline__ int blk(int KC, int nt, int kc, int slot) {
    return ((nt * KC + kc) * 2 + slot) << 9;
}
__device__ __forceinline__ int eix(int col, int kl) { // elem index in block
    return ((col | ((kl >> 3) << 5)) << 3) + (kl & 7);
}

__device__ __forceinline__ float rcp_(float x) { return __builtin_amdgcn_rcpf(x); }

// gate EW: acc quad = {i,f,g,o} preacts (bias MFMA-folded). 4 exp + 3 rcp.
__device__ __forceinline__ float lstm_ew1(f32x4 acc, float& cst) {
    float ei = __expf(-acc[0]);
    float ef = __expf(-acc[1]);
    float eg = __expf(2.0f * fminf(acc[2], 40.0f));
    float eo = __expf(-acc[3]);
    float c = rcp_(1.0f + ef) * cst + (eg - 1.0f) * rcp_((1.0f + ei) * (eg + 1.0f));
    cst = c;
    float ec = __expf(2.0f * fminf(c, 40.0f));
    return (ec - 1.0f) * rcp_((1.0f + eo) * (ec + 1.0f));
}

__device__ __forceinline__ ushort bfu(float f) {
    union { bf16 b; ushort u; } v; v.b = __float2bfloat16(f); return v.u;
}

// pack one K=16 weight fragment; assumed k-map k = ((lane>>5)<<3)+j, rows = lane&31
// (self-consistent with the B-fragment layout written by eix(); errors cancel)
template <typename F>
__device__ __forceinline__ bf16x8 mk32(int lane, F val) { // val(k), k in [0,16)
    union { bf16x8 v; bf16 h[8]; } u;
#pragma unroll
    for (int j = 0; j < 8; ++j)
        u.h[j] = __float2bfloat16(val(((lane >> 5) << 3) + j));
    return u.v;
}

__global__ void __launch_bounds__(THREADS, 4)
lstm_fused(const float* __restrict__ x, const float* __restrict__ y,
           const float* __restrict__ Wih1, const float* __restrict__ Whh1,
           const float* __restrict__ bih1, const float* __restrict__ bhh1,
           const float* __restrict__ Wih2, const float* __restrict__ Whh2,
           const float* __restrict__ bih2, const float* __restrict__ bhh2,
           const float* __restrict__ Wih3, const float* __restrict__ Whh3,
           const float* __restrict__ bih3, const float* __restrict__ bhh3,
           const float* __restrict__ W1, const float* __restrict__ b1,
           const float* __restrict__ W2, const float* __restrict__ b2,
           const float* __restrict__ W3, const float* __restrict__ b3,
           const float* __restrict__ W4, const float* __restrict__ b4,
           float* __restrict__ out) {
    extern __shared__ char smem[];
    bf16* sb = (bf16*)smem;
    const int tid = threadIdx.x;
    const int wave = tid >> 6, lane = tid & 63;
    const int ln31 = lane & 31, hi = lane >> 5;
    const int b0 = blockIdx.x * 64;

    // ---- roles ----
    // w0-8 : L2 Mtile=wave, W[0..9]
    // w9-12: L3 Mtile=wave-9, W[0..8]; w9/w10 also FC34 Nt=wave-9, W[9..10]
    // w11/12: y-stage half=wave-11
    // w13  : L1 Mt0 W[0..1] + FC2 Mt0 W[2..6] + x-stage
    // w14  : L1 Mt1 W[0..1] + FC2 Mt1 W[2..6] + FC1 Mt0 W[7..9]
    // w15  : FC2 Mt2 W[2..6] + FC1 Mt1 W[7..9]
    bf16x8 W[11];
#pragma unroll
    for (int i = 0; i < 11; ++i) W[i] = bf16x8{0, 0, 0, 0, 0, 0, 0, 0};

    if (wave < 9) { // LSTM2: rows n=32w+ln31, gate interleave n=h*4+g
        int n = 32 * wave + ln31;
        int r = (n & 3) * 72 + (n >> 2);
        float bias = bih2[r] + bhh2[r];
#pragma unroll
        for (int kc = 0; kc < 10; ++kc)
            W[kc] = mk32(lane, [&](int k) {
                int kg = kc * 16 + k;
                return kg < 72 ? Wih2[r * 72 + kg]
                     : (kg < 144 ? Whh2[r * 72 + (kg - 72)]
                     : (kg == 144 ? bias : 0.0f)); });
    } else if (wave < 13) { // LSTM3
        int n = 32 * (wave - 9) + ln31;
        int r = (n & 3) * 32 + (n >> 2);
        float bias = bih3[r] + bhh3[r];
        W[0] = mk32(lane, [&](int k) {
            return k < 2 ? 0.0f : Wih3[r * 88 + (k - 2)]; });
        W[1] = mk32(lane, [&](int k) {
            int kg = 16 + k;
            return kg < 18 ? Wih3[r * 88 + (kg - 2)] : (kg == 18 ? bias : 0.0f); });
#pragma unroll
        for (int i = 0; i < 5; ++i)
            W[2 + i] = mk32(lane, [&](int k) {
                int kg = 64 + i * 16 + k;
                return kg < 72 ? 0.0f : Wih3[r * 88 + 16 + (kg - 72)]; });
#pragma unroll
        for (int i = 0; i < 2; ++i)
            W[7 + i] = mk32(lane, [&](int k) { return Whh3[r * 32 + i * 16 + k]; });
        if (wave < 11) { // FC34: W3 rows u=ln31 (valid<16)
#pragma unroll
            for (int i = 0; i < 2; ++i)
                W[9 + i] = mk32(lane, [&](int k) {
                    return (ln31 < 16) ? W3[ln31 * 32 + i * 16 + k] : 0.0f; });
        }
    } else {
        if (wave < 15) { // L1 Mtile wave-13
            int n = 32 * (wave - 13) + ln31;
            int r = (n & 3) * 16 + (n >> 2);
            float bias = bih1[r] + bhh1[r];
            W[0] = mk32(lane, [&](int k) {
                return k < 2 ? Wih1[r * 2 + k] : Whh1[r * 16 + (k - 2)]; });
            W[1] = mk32(lane, [&](int k) {
                int kg = 16 + k;
                return kg < 18 ? Whh1[r * 16 + (kg - 2)] : (kg == 18 ? bias : 0.0f); });
        }
        { // FC2 Mtile wave-13 (rows may exceed 71 -> zero)
            int n2 = 32 * (wave - 13) + ln31;
#pragma unroll
            for (int kc = 0; kc < 5; ++kc)
                W[2 + kc] = mk32(lane, [&](int k) {
                    int kg = kc * 16 + k;
                    if (n2 >= 72) return 0.0f;
                    return kg < 64 ? W2[n2 * 64 + kg] : (kg == 64 ? b2[n2] : 0.0f); });
        }
        if (wave >= 14) { // FC1 Mtile wave-14
            int f = 32 * (wave - 14) + ln31;
#pragma unroll
            for (int kc = 0; kc < 3; ++kc)
                W[7 + kc] = mk32(lane, [&](int k) {
                    int kg = kc * 16 + k;
                    return kg < 36 ? W1[f * 36 + kg] : (kg == 36 ? b1[f] : 0.0f); });
        }
    }

    // ---- zero LDS ----
    {
        int4* z = (int4*)sb;
        int4 zv = {0, 0, 0, 0};
        for (int i = tid; i < LDS_BYTES / 16; i += THREADS) z[i] = zv;
    }
    __syncthreads();
    // ---- stage y(0)->AY[s0], y(1)->AY[s1], x(0)->A1[s0], bias lanes ----
    for (int it = tid; it < 2 * 2304; it += THREADS) {
        int slot = it / 2304, r2 = it - slot * 2304;
        int m = r2 / 36, k = r2 - m * 36;
        sb[O_AY + blk(3, m >> 5, k >> 4, slot) + eix(m & 31, k & 15)] =
            __float2bfloat16(y[(size_t)(b0 + m) * 900 + slot * 36 + k]);
    }
    if (tid < 128) {
        int m = tid >> 1, k = tid & 1;
        sb[O_A1 + blk(2, m >> 5, 0, 0) + eix(m & 31, k)] =
            __float2bfloat16(x[(size_t)(b0 + m) * 50 + k]);
    }
    {
        const bf16 one = __float2bfloat16(1.0f);
        int i = tid & 127, col = i & 31, nt = (i >> 5) & 1, s = (i >> 6) & 1;
        if (tid < 128)       sb[O_A1 + blk(2, nt, 1, s) + eix(col, 2)] = one;   // k=18
        else if (tid < 256)  sb[O_AY + blk(3, nt, 2, s) + eix(col, 4)] = one;   // k=36
        else if (tid < 384)  sb[O_AT1 + blk(5, nt, 4, s) + eix(col, 0)] = one;  // k=64
        else if (tid < 512)  sb[O_A2 + blk(10, nt, 9, s) + eix(col, 0)] = one;  // k=144
    }
    __syncthreads();
    // ---- prologue FC1(0)->AT1[1], FC1(1)->AT1[0] on w14-15 ----
    if (wave >= 14) {
#pragma unroll
        for (int s = 0; s < 2; ++s) {
#pragma unroll
            for (int nt = 0; nt < 2; ++nt) {
                f32x16 acc = Z16;
#pragma unroll
                for (int kc = 0; kc < 3; ++kc) {
                    bf16x8 a = *(const bf16x8*)(sb + O_AY + blk(3, nt, kc, s) + (lane << 3));
                    acc = MFMA32(W[7 + kc], a, acc, 0, 0, 0);
                }
#pragma unroll
                for (int qq = 0; qq < 4; ++qq) {
                    int f0 = 32 * (wave - 14) + 8 * qq + 4 * hi;
                    ushort4 pk;
                    pk.x = bfu(fmaxf(acc[4 * qq + 0], 0.f));
                    pk.y = bfu(fmaxf(acc[4 * qq + 1], 0.f));
                    pk.z = bfu(fmaxf(acc[4 * qq + 2], 0.f));
                    pk.w = bfu(fmaxf(acc[4 * qq + 3], 0.f));
                    *(ushort4*)(sb + O_AT1 + blk(5, nt, f0 >> 4, s ^ 1) + eix(ln31, f0 & 15)) = pk;
                }
            }
        }
    }
    __syncthreads();
    // ---- prologue FC2(0)->A2[s0] (w13-15, reads AT1[s1]); y(2)->AY[s0] (w11-12) ----
    if (wave >= 13) {
#pragma unroll
        for (int nt = 0; nt < 2; ++nt) {
            f32x16 acc = Z16;
#pragma unroll
            for (int kc = 0; kc < 5; ++kc) {
                bf16x8 a = *(const bf16x8*)(sb + O_AT1 + blk(5, nt, kc, 1) + (lane << 3));
                acc = MFMA32(W[2 + kc], a, acc, 0, 0, 0);
            }
#pragma unroll
            for (int qq = 0; qq < 4; ++qq) {
                int n0 = 32 * (wave - 13) + 8 * qq + 4 * hi;
                if (n0 < 72) {
                    ushort4 pk;
                    pk.x = bfu(acc[4 * qq + 0]); pk.y = bfu(acc[4 * qq + 1]);
                    pk.z = bfu(acc[4 * qq + 2]); pk.w = bfu(acc[4 * qq + 3]);
                    *(ushort4*)(sb + O_A2 + blk(10, nt, n0 >> 4, 0) + eix(ln31, n0 & 15)) = pk;
                }
            }
        }
    } else if (wave == 11 || wave == 12) {
        const int half = wave - 11;
        const int m = 32 * half + (lane >> 1);
        const float* yp = y + (size_t)(b0 + m) * 900 + 2 * 36;
#pragma unroll
        for (int c = (lane & 1); c < 9; c += 2) {
            float4 v = *(const float4*)(yp + 4 * c);
            ushort4 pk;
            pk.x = bfu(v.x); pk.y = bfu(v.y); pk.z = bfu(v.z); pk.w = bfu(v.w);
            int k0 = 4 * c;
            *(ushort4*)(sb + O_AY + blk(3, half, k0 >> 4, 0) + eix(m & 31, k0 & 15)) = pk;
        }
    }
    float cS[2][4] = {};   // per-role LSTM state (L2 / L3 / L1)
    __syncthreads();

    // ======== main loop: ONE barrier per phase ========
    for (int t = 0; t <= 25; ++t) {
        const int p = t & 1, q = p ^ 1;

        if (wave < 9) { // ---- LSTM2(t), t<=24 ----
            if (t <= 24) {
#pragma unroll
                for (int nt = 0; nt < 2; ++nt) {
                    f32x16 acc = Z16;
#pragma unroll
                    for (int kc = 0; kc < 10; ++kc) {
                        bf16x8 a = *(const bf16x8*)(sb + O_A2 + blk(10, nt, kc, p) + (lane << 3));
                        acc = MFMA32(W[kc], a, acc, 0, 0, 0);
                    }
#pragma unroll
                    for (int qq = 0; qq < 4; ++qq) {
                        f32x4 g4 = {acc[4 * qq], acc[4 * qq + 1], acc[4 * qq + 2], acc[4 * qq + 3]};
                        float hv = lstm_ew1(g4, cS[nt][qq]);
                        int k = 72 + 8 * wave + 2 * qq + hi;
                        sb[O_A2 + blk(10, nt, k >> 4, q) + eix(ln31, k & 15)] = __float2bfloat16(hv);
                    }
                }
            }
        } else if (wave < 13) { // ---- LSTM3(t-1) + FC34(t-2) + y-stage ----
            if (t >= 1) {
                const int M3 = wave - 9;
#pragma unroll
                for (int nt = 0; nt < 2; ++nt) {
                    f32x16 acc = Z16;
                    {
                        bf16x8 a0 = *(const bf16x8*)(sb + O_A1 + blk(2, nt, 0, p) + (lane << 3));
                        acc = MFMA32(W[0], a0, acc, 0, 0, 0);
                        bf16x8 a1 = *(const bf16x8*)(sb + O_A1 + blk(2, nt, 1, p) + (lane << 3));
                        acc = MFMA32(W[1], a1, acc, 0, 0, 0);
                    }
#pragma unroll
                    for (int i = 0; i < 5; ++i) {
                        bf16x8 a = *(const bf16x8*)(sb + O_A2 + blk(10, nt, 4 + i, p) + (lane << 3));
                        acc = MFMA32(W[2 + i], a, acc, 0, 0, 0);
                    }
#pragma unroll
                    for (int i = 0; i < 2; ++i) {
                        bf16x8 a = *(const bf16x8*)(sb + O_AH3 + blk(2, nt, i, p) + (lane << 3));
                        acc = MFMA32(W[7 + i], a, acc, 0, 0, 0);
                    }
#pragma unroll
                    for (int qq = 0; qq < 4; ++qq) {
                        f32x4 g4 = {acc[4 * qq], acc[4 * qq + 1], acc[4 * qq + 2], acc[4 * qq + 3]};
                        float hv = lstm_ew1(g4, cS[nt][qq]);
                        int k = 8 * M3 + 2 * qq + hi;
                        sb[O_AH3 + blk(2, nt, k >> 4, q) + eix(ln31, k & 15)] = __float2bfloat16(hv);
                    }
                }
            }
            if (wave < 11) { // FC34(t-2), Nt = wave-9
                if (t >= 2) {
                    const int ntw = wave - 9;
                    f32x16 acc = Z16;
#pragma unroll
                    for (int i = 0; i < 2; ++i) {
                        bf16x8 a = *(const bf16x8*)(sb + O_AH3 + blk(2, ntw, i, p) + (lane << 3));
                        acc = MFMA32(W[9 + i], a, acc, 0, 0, 0);
                    }
                    float s0 = 0.f, s1 = 0.f;
#pragma unroll
                    for (int qq = 0; qq < 2; ++qq) {
                        int r = 8 * qq + 4 * hi;
                        float4 b3v = *(const float4*)(b3 + r);
                        float4 w0v = *(const float4*)(W4 + r);
                        float4 w1v = *(const float4*)(W4 + 16 + r);
#pragma unroll
                        for (int s = 0; s < 4; ++s) {
                            float u = fmaxf(acc[4 * qq + s] + b3v[s], 0.f);
                            s0 = fmaf(u, w0v[s], s0);
                            s1 = fmaf(u, w1v[s], s1);
                        }
                    }
                    s0 += __shfl_xor(s0, 32); s1 += __shfl_xor(s1, 32);
                    if (lane < 32) {
                        float2 o; o.x = s0 + b4[0]; o.y = s1 + b4[1];
                        *(float2*)(out + (size_t)(b0 + 32 * ntw + ln31) * 50 + (t - 2) * 2) = o;
                    }
                }
            } else if (t <= 21) { // y(t+3) stage, half = wave-11
                const int half = wave - 11;
                const int m = 32 * half + (lane >> 1);
                const float* yp = y + (size_t)(b0 + m) * 900 + (t + 3) * 36;
#pragma unroll
                for (int c = (lane & 1); c < 9; c += 2) {
                    float4 v = *(const float4*)(yp + 4 * c);
                    ushort4 pk;
                    pk.x = bfu(v.x); pk.y = bfu(v.y); pk.z = bfu(v.z); pk.w = bfu(v.w);
                    int k0 = 4 * c;
                    *(ushort4*)(sb + O_AY + blk(3, half, k0 >> 4, q) + eix(m & 31, k0 & 15)) = pk;
                }
            }
        } else { // ---- w13-15: L1(t) + FC2(t+1) + FC1(t+2) + x-stage ----
            if (t <= 24 && wave < 15) { // L1, Mtile wave-13
                const int M1 = wave - 13;
#pragma unroll
                for (int nt = 0; nt < 2; ++nt) {
                    f32x16 acc = Z16;
#pragma unroll
                    for (int i = 0; i < 2; ++i) {
                        bf16x8 a = *(const bf16x8*)(sb + O_A1 + blk(2, nt, i, p) + (lane << 3));
                        acc = MFMA32(W[i], a, acc, 0, 0, 0);
                    }
#pragma unroll
                    for (int qq = 0; qq < 4; ++qq) {
                        f32x4 g4 = {acc[4 * qq], acc[4 * qq + 1], acc[4 * qq + 2], acc[4 * qq + 3]};
                        float hv = lstm_ew1(g4, cS[nt][qq]);
                        int k = 2 + 8 * M1 + 2 * qq + hi;
                        sb[O_A1 + blk(2, nt, k >> 4, q) + eix(ln31, k & 15)] = __float2bfloat16(hv);
                    }
                }
            }
            if (t <= 23 && wave == 13) { // x(t+1) -> A1[q]
                const int nt = lane >> 5;
                float2 xv = *(const float2*)(x + (size_t)(b0 + lane) * 50 + (t + 1) * 2);
                union { uint u; ushort s[2]; } xu;
                xu.s[0] = bfu(xv.x); xu.s[1] = bfu(xv.y);
                *(uint*)(sb + O_A1 + blk(2, nt, 0, q) + (ln31 << 3)) = xu.u;
            }
            if (t <= 22 && wave >= 14) { // FC1(t+2), Mtile wave-14
#pragma unroll
                for (int nt = 0; nt < 2; ++nt) {
                    f32x16 acc = Z16;
#pragma unroll
                    for (int kc = 0; kc < 3; ++kc) {
                        bf16x8 a = *(const bf16x8*)(sb + O_AY + blk(3, nt, kc, p) + (lane << 3));
                        acc = MFMA32(W[7 + kc], a, acc, 0, 0, 0);
                    }
#pragma unroll
                    for (int qq = 0; qq < 4; ++qq) {
                        int f0 = 32 * (wave - 14) + 8 * qq + 4 * hi;
                        ushort4 pk;
                        pk.x = bfu(fmaxf(acc[4 * qq + 0], 0.f));
                        pk.y = bfu(fmaxf(acc[4 * qq + 1], 0.f));
                        pk.z = bfu(fmaxf(acc[4 * qq + 2], 0.f));
                        pk.w = bfu(fmaxf(acc[4 * qq + 3], 0.f));
                        *(ushort4*)(sb + O_AT1 + blk(5, nt, f0 >> 4, q) + eix(ln31, f0 & 15)) = pk;
                    }
                }
            }
            if (t <= 23) { // FC2(t+1), Mtile wave-13
#pragma unroll
                for (int nt = 0; nt < 2; ++nt) {
                    f32x16 acc = Z16;
#pragma unroll
                    for (int kc = 0; kc < 5; ++kc) {
                        bf16x8 a = *(const bf16x8*)(sb + O_AT1 + blk(5, nt, kc, p) + (lane << 3));
                        acc = MFMA32(W[2 + kc], a, acc, 0, 0, 0);
                    }
#pragma unroll
                    for (int qq = 0; qq < 4; ++qq) {
                        int n0 = 32 * (wave - 13) + 8 * qq + 4 * hi;
                        if (n0 < 72) {
                            ushort4 pk;
                            pk.x = bfu(acc[4 * qq + 0]); pk.y = bfu(acc[4 * qq + 1]);
                            pk.z = bfu(acc[4 * qq + 2]); pk.w = bfu(acc[4 * qq + 3]);
                            *(ushort4*)(sb + O_A2 + blk(10, nt, n0 >> 4, q) + eix(ln31, n0 & 15)) = pk;
                        }
                    }
                }
            }
        }
        __syncthreads();
    }

    // ---- epilogue: FC34 for t=24; h3(24) in AH3 slot 0 ----
    if (wave == 9 || wave == 10) {
        const int ntw = wave - 9;
        f32x16 acc = Z16;
#pragma unroll
        for (int i = 0; i < 2; ++i) {
            bf16x8 a = *(const bf16x8*)(sb + O_AH3 + blk(2, ntw, i, 0) + (lane << 3));
            acc = MFMA32(W[9 + i], a, acc, 0, 0, 0);
        }
        float s0 = 0.f, s1 = 0.f;
#pragma unroll
        for (int qq = 0; qq < 2; ++qq) {
            int r = 8 * qq + 4 * hi;
            float4 b3v = *(const float4*)(b3 + r);
            float4 w0v = *(const float4*)(W4 + r);
            float4 w1v = *(const float4*)(W4 + 16 + r);
#pragma unroll
            for (int s = 0; s < 4; ++s) {
                float u = fmaxf(acc[4 * qq + s] + b3v[s], 0.f);
                s0 = fmaf(u, w0v[s], s0);
                s1 = fmaf(u, w1v[s], s1);
            }
        }
        s0 += __shfl_xor(s0, 32); s1 += __shfl_xor(s1, 32);
        if (lane < 32) {
            float2 o; o.x = s0 + b4[0]; o.y = s1 + b4[1];
            *(float2*)(out + (size_t)(b0 + 32 * ntw + ln31) * 50 + 24 * 2) = o;
        }
    }
}

extern "C" void kernel_launch(void* const* d_in, const int* in_sizes, int n_in,
                              void* d_out, int out_size, void* d_ws, size_t ws_size,
                              hipStream_t stream) {
    (void)in_sizes; (void)n_in; (void)d_ws; (void)ws_size; (void)out_size;
    hipFuncSetAttribute((const void*)lstm_fused,
                        hipFuncAttributeMaxDynamicSharedMemorySize, LDS_BYTES);
    lstm_fused<<<dim3(2048), dim3(THREADS), LDS_BYTES, stream>>>(
        (const float*)d_in[0], (const float*)d_in[1],
        (const float*)d_in[2], (const float*)d_in[3],
        (const float*)d_in[4], (const float*)d_in[5],
        (const float*)d_in[6], (const float*)d_in[7],
        (const float*)d_in[8], (const float*)d_in[9],
        (const float*)d_in[10], (const float*)d_in[11],
        (const float*)d_in[12], (const float*)d_in[13],
        (const float*)d_in[14], (const float*)d_in[15],
        (const float*)d_in[16], (const float*)d_in[17],
        (const float*)d_in[18], (const float*)d_in[19],
        (const float*)d_in[20], (const float*)d_in[21],
        (float*)d_out);
}